// Round 1
// baseline (101.041 us; speedup 1.0000x reference)
//
#include <hip/hip_runtime.h>

// MPS layer collapses algebraically:
//   out[b,o] = p[b]*q[o] + bias[o]
//   p[b] = prod_i inputs[b,i];  q = (1^T * prod_i C_i) @ projection
// Kernels: K1/K2 tree-reduce the 1024-core matrix chain, K3 finishes the
// chain as a vector and projects, K4 does the memory-bound batch pass.

// ---- 32x32 fp32 matmul, A,B,C in LDS, 256 threads, thread = (row j, col-quad kq)
__device__ __forceinline__ void mm32(const float* __restrict__ A,
                                     const float* __restrict__ B,
                                     float* __restrict__ C, int tid) {
    const int j = tid >> 3;      // 0..31 output row
    const int kq = tid & 7;      // 0..7  -> output cols 4kq..4kq+3
    float a[32];
    const float4* __restrict__ A4 = (const float4*)(A + j * 32);
#pragma unroll
    for (int t = 0; t < 8; ++t) {
        float4 v = A4[t];
        a[4 * t + 0] = v.x; a[4 * t + 1] = v.y;
        a[4 * t + 2] = v.z; a[4 * t + 3] = v.w;
    }
    const float4* __restrict__ B4 = (const float4*)B;
    float4 acc = make_float4(0.f, 0.f, 0.f, 0.f);
#pragma unroll
    for (int m = 0; m < 32; ++m) {
        float4 b = B4[m * 8 + kq];
        acc.x = fmaf(a[m], b.x, acc.x);
        acc.y = fmaf(a[m], b.y, acc.y);
        acc.z = fmaf(a[m], b.z, acc.z);
        acc.w = fmaf(a[m], b.w, acc.w);
    }
    ((float4*)(C + j * 32))[kq] = acc;
}

// ---- K1: 256 WGs, each computes C_{4s} C_{4s+1} C_{4s+2} C_{4s+3}
__global__ __launch_bounds__(256) void k_seg4(const float* __restrict__ cores,
                                              float* __restrict__ l1) {
    __shared__ __align__(16) float c[4 * 1024];
    __shared__ __align__(16) float ping[1024];
    __shared__ __align__(16) float pong[1024];
    const int tid = threadIdx.x;
    const int s = blockIdx.x;
    const float4* src = (const float4*)(cores + (size_t)s * 4096);
    float4* cd = (float4*)c;
#pragma unroll
    for (int t = 0; t < 4; ++t) cd[tid + 256 * t] = src[tid + 256 * t];
    __syncthreads();
    mm32(c, c + 1024, ping, tid);
    __syncthreads();
    mm32(ping, c + 2048, pong, tid);
    __syncthreads();
    mm32(pong, c + 3072, ping, tid);
    __syncthreads();
    ((float4*)(l1 + (size_t)s * 1024))[tid] = ((const float4*)ping)[tid];
}

// ---- K2: 32 WGs, each multiplies 8 consecutive level-1 matrices (in order)
__global__ __launch_bounds__(256) void k_seg8(const float* __restrict__ l1,
                                              float* __restrict__ l2) {
    __shared__ __align__(16) float m[8 * 1024];
    __shared__ __align__(16) float ping[1024];
    __shared__ __align__(16) float pong[1024];
    const int tid = threadIdx.x;
    const int s = blockIdx.x;
    const float4* src = (const float4*)(l1 + (size_t)s * 8192);
    float4* md = (float4*)m;
#pragma unroll
    for (int t = 0; t < 8; ++t) md[tid + 256 * t] = src[tid + 256 * t];
    __syncthreads();
    mm32(m, m + 1024, ping, tid);
    __syncthreads();
    float* A = ping;
    float* C = pong;
    for (int t = 2; t < 8; ++t) {
        mm32(A, m + t * 1024, C, tid);
        __syncthreads();
        float* tmp = A; A = C; C = tmp;
    }
    // result is in A after final swap
    ((float4*)(l2 + (size_t)s * 1024))[tid] = ((const float4*)A)[tid];
}

// ---- K3: single wave. w^T = 1^T M_0 ... M_31 via 32 matvec steps
//      (v replicated per-lane, LDS scratch broadcast), then q = w @ projection.
__global__ __launch_bounds__(64) void k_chain(const float* __restrict__ l2,
                                              const float* __restrict__ proj,
                                              float* __restrict__ q) {
    __shared__ __align__(16) float M[2][2048];   // double-buffered: 2 mats/chunk
    __shared__ __align__(16) float sc[2][32];
    const int lane = threadIdx.x;   // 0..63 (one wave)
    const int k = lane & 31;
    const float4* src = (const float4*)l2;
    float4 pf[8];
#pragma unroll
    for (int t = 0; t < 8; ++t) pf[t] = src[lane + 64 * t];
#pragma unroll
    for (int t = 0; t < 8; ++t) ((float4*)M[0])[lane + 64 * t] = pf[t];
    __syncthreads();
    float v[32];
#pragma unroll
    for (int j = 0; j < 32; ++j) v[j] = 1.0f;
    for (int c = 0; c < 16; ++c) {
        if (c + 1 < 16) {   // prefetch next chunk while chaining this one
#pragma unroll
            for (int t = 0; t < 8; ++t)
                pf[t] = src[(c + 1) * 512 + lane + 64 * t];
        }
        const float* Mc = M[c & 1];
#pragma unroll
        for (int s = 0; s < 2; ++s) {
            const float* mat = Mc + s * 1024;
            float acc = 0.f;
#pragma unroll
            for (int j = 0; j < 32; ++j)
                acc = fmaf(v[j], mat[j * 32 + k], acc);   // column k: conflict-free
            const int pb = (2 * c + s) & 1;
            if (lane < 32) sc[pb][k] = acc;
            __syncthreads();
#pragma unroll
            for (int j = 0; j < 32; ++j) v[j] = sc[pb][j];   // broadcast
        }
        if (c + 1 < 16) {
            __syncthreads();
#pragma unroll
            for (int t = 0; t < 8; ++t)
                ((float4*)M[(c + 1) & 1])[lane + 64 * t] = pf[t];
            __syncthreads();
        }
    }
    // q[o] = sum_j w[j] * proj[j,o], proj row = 128 float4s
    const float4* P4 = (const float4*)proj;
    float4* q4 = (float4*)q;
#pragma unroll
    for (int h = 0; h < 2; ++h) {
        const int o4 = h * 64 + lane;
        float4 acc = make_float4(0.f, 0.f, 0.f, 0.f);
#pragma unroll
        for (int j = 0; j < 32; ++j) {
            float4 pv = P4[j * 128 + o4];
            acc.x = fmaf(v[j], pv.x, acc.x);
            acc.y = fmaf(v[j], pv.y, acc.y);
            acc.z = fmaf(v[j], pv.z, acc.z);
            acc.w = fmaf(v[j], pv.w, acc.w);
        }
        q4[o4] = acc;
    }
}

// ---- K4: memory-bound pass. One wave per batch row: p[b] = prod of row,
//      then out[b,:] = p*q + bias. 4 rows per 256-thread block.
__global__ __launch_bounds__(256) void k_out(const float* __restrict__ inputs,
                                             const float* __restrict__ q,
                                             const float* __restrict__ bias,
                                             float* __restrict__ out) {
    const int lane = threadIdx.x & 63;
    const int wid = threadIdx.x >> 6;
    const int row = blockIdx.x * 4 + wid;
    const float4* in4 = (const float4*)(inputs + (size_t)row * 1024);
    float4 x0 = in4[lane];
    float4 x1 = in4[lane + 64];
    float4 x2 = in4[lane + 128];
    float4 x3 = in4[lane + 192];
    float p = ((x0.x * x0.y) * (x0.z * x0.w)) * ((x1.x * x1.y) * (x1.z * x1.w)) *
              ((x2.x * x2.y) * (x2.z * x2.w)) * ((x3.x * x3.y) * (x3.z * x3.w));
#pragma unroll
    for (int msk = 1; msk < 64; msk <<= 1) p *= __shfl_xor(p, msk);
    const float4* q4 = (const float4*)q;
    const float4* b4 = (const float4*)bias;
    float4* o4 = (float4*)(out + (size_t)row * 512);
#pragma unroll
    for (int t = 0; t < 2; ++t) {
        float4 qq = q4[lane + 64 * t];
        float4 bb = b4[lane + 64 * t];
        float4 r;
        r.x = fmaf(p, qq.x, bb.x);
        r.y = fmaf(p, qq.y, bb.y);
        r.z = fmaf(p, qq.z, bb.z);
        r.w = fmaf(p, qq.w, bb.w);
        o4[lane + 64 * t] = r;
    }
}

extern "C" void kernel_launch(void* const* d_in, const int* in_sizes, int n_in,
                              void* d_out, int out_size, void* d_ws, size_t ws_size,
                              hipStream_t stream) {
    const float* inputs = (const float*)d_in[0];   // [4096,1024]
    const float* cores  = (const float*)d_in[1];   // [1024,32,32]
    const float* proj   = (const float*)d_in[2];   // [32,512]
    const float* bias   = (const float*)d_in[3];   // [512]
    float* out = (float*)d_out;                    // [4096,512]
    float* w  = (float*)d_ws;
    float* l1 = w;                          // 256 * 1024 floats (1 MB)
    float* l2 = w + 256 * 1024;             // 32 * 1024 floats (128 KB)
    float* q  = w + 256 * 1024 + 32 * 1024; // 512 floats

    k_seg4<<<256, 256, 0, stream>>>(cores, l1);
    k_seg8<<<32, 256, 0, stream>>>(l1, l2);
    k_chain<<<1, 64, 0, stream>>>(l2, proj, q);
    k_out<<<1024, 256, 0, stream>>>(inputs, q, bias, out);
}